// Round 8
// baseline (43.049 us; speedup 1.0000x reference)
//
#include <hip/hip_runtime.h>
#include <math.h>

#define N_PED 768
#define NW 12  // 768/64 u64 words per adjacency column

// ---------------- ws layout (bytes) ----------------
// adjT16  : [768*48] u16  @ 0      (73728)  column-major bits, 16-bit row-chunks
//           u64 view: word (c, I) at adjT[c*12+I]; chunk k = bits [16k,16k+16)
// rowmaxT : [12][768] int @ 73728  (36864)  per-tile row max col (or -1), transposed
// total 110592 bytes

// KB: fused per-node features + pairwise dist + bit-transpose.
// Block = (tile I,J; row-chunk of 16 rows). Upper tiles (I<J) structurally
// zero: fill and exit. Compute blocks: recompute A (f64, exact k1 ordering)
// for the 64 col nodes + 16 row nodes in LDS, then 4 waves x 4 rows of
// 64-lane pair evaluation -> ballot words -> u16 transpose store.
__global__ __launch_bounds__(256) void kb(
    const float* __restrict__ va, const float* __restrict__ vr,
    const float* __restrict__ velw, const float* __restrict__ velb,
    const float* __restrict__ g1w, const float* __restrict__ g1b,
    const float* __restrict__ gam, const float* __restrict__ bet,
    const float* __restrict__ g2w, const float* __restrict__ g2b,
    unsigned short* __restrict__ adjT16, int* __restrict__ rowmaxT) {
  int bid = blockIdx.x;
  int tile = bid >> 2, chunk = bid & 3;
  int I = tile / NW, J = tile % NW;
  int tid = threadIdx.x;
  if (I < J) {  // structurally zero
    if (tid < 64) adjT16[(J * 64 + tid) * 48 + I * 4 + chunk] = 0;
    if (tid < 16) rowmaxT[J * N_PED + I * 64 + chunk * 16 + tid] = -1;
    return;
  }
  __shared__ double Acol[16][64];
  __shared__ double Arow[16][16];
  __shared__ unsigned long long roww[16];

  // ---- A compute: jobs 0..63 col nodes, 64..79 row nodes; 2 threads/job ----
  {
    int job = tid >> 1, half = tid & 1;
    bool isrow = (job >= 64);
    bool active = (job < 80) && !(isrow && I == J);
    if (active) {
      int node = isrow ? (I * 64 + chunk * 16 + (job - 64)) : (J * 64 + job);
      double F[32];
#pragma unroll
      for (int cc = 0; cc < 2; ++cc)
#pragma unroll
        for (int t = 0; t < 8; ++t)
          F[cc * 8 + t] = (double)va[(cc * 8 + t) * N_PED + node];
#pragma unroll
      for (int o = 0; o < 2; ++o)
#pragma unroll
        for (int t = 0; t < 8; ++t)
          F[(2 + o) * 8 + t] = (double)velb[o]
              + (double)velw[o * 2 + 0] * (double)vr[(0 + t) * N_PED + node]
              + (double)velw[o * 2 + 1] * (double)vr[(8 + t) * N_PED + node];
      for (int o = half * 8; o < half * 8 + 8; ++o) {
        double s = 0.0;
#pragma unroll
        for (int k = 0; k < 32; ++k) s += (double)g1w[o * 32 + k] * F[k];
        if (isrow) Arow[o][job - 64] = s;
        else Acol[o][job] = s;
      }
    }
  }
  __syncthreads();

  // ---- effective MLP params (uniform, exact k1 ordering) ----
  double w2[16], b1[16];
  const double inv_std = 1.0 / sqrt(1.0 + 1e-5);
#pragma unroll
  for (int o = 0; o < 16; ++o) {
    w2[o] = (double)g2w[o] * inv_std * (double)gam[o];
    b1[o] = (double)g1b[o];
  }
  double c0 = (double)g2b[0];
#pragma unroll
  for (int o = 0; o < 16; ++o) c0 += (double)g2w[o] * (double)bet[o];

  int w = tid >> 6, lane = tid & 63;
  int c = J * 64 + lane;
  double Ac[16];
#pragma unroll
  for (int o = 0; o < 16; ++o) Ac[o] = Acol[o][lane];

  for (int q = 0; q < 4; ++q) {
    int rr = w * 4 + q;
    int r = I * 64 + chunk * 16 + rr;
    double x1 = 0.0, x2 = 0.0;
#pragma unroll
    for (int o = 0; o < 16; ++o) {
      double Av = (I == J) ? Acol[o][chunk * 16 + rr] : Arow[o][rr];
      double s = Av - Ac[o];
      x1 += w2[o] * fmax(s + b1[o], 0.0);
      x2 += w2[o] * fmax(b1[o] - s, 0.0);
    }
    double dist = 0.5 * (exp(x1 + c0) + exp(x2 + c0));
    bool bit = (c < r) && (dist <= 1.0);
    unsigned long long word = __ballot(bit ? 1 : 0);
    if (lane == 0) {
      roww[rr] = word;
      rowmaxT[J * N_PED + r] =
          word ? (J * 64 + 63 - __clzll((long long)word)) : -1;
    }
  }
  __syncthreads();

  if (tid < 64) {  // transpose 16 rows x 64 cols -> u16 per col
    unsigned m = 0;
#pragma unroll
    for (int rr = 0; rr < 16; ++rr)
      m |= (unsigned)((roww[rr] >> tid) & 1ull) << rr;
    adjT16[(J * 64 + tid) * 48 + I * 4 + chunk] = (unsigned short)m;
  }
}

// KC: fused grouping + pooling + epilogue. One block, 768 threads.
// Grouping: pointer-doubling over the successor forest (proved R4):
//   v0[n]   = rowcm[n] >= 0 ? rowcm[n] : n
//   succ(n) = first set bit in column v0[n] strictly below row n (self if none)
//   label(n) = v0 at the root; labels ranked ascending -> group ids.
// Pooling: fixed-point (2^32) i64 LDS atomics -> order-independent,
// deterministic; normalized in place to double. Epilogue: time-mix +
// channel-mix per thread n.
__global__ __launch_bounds__(768) void kc(
    const unsigned long long* __restrict__ adjT,
    const int* __restrict__ rowmaxT,
    const float* __restrict__ vrel, const float* __restrict__ wt,
    const float* __restrict__ wc, float* __restrict__ out) {
  __shared__ long long poolFix[16 * N_PED];  // 96 KB; doubles after normalize
  __shared__ int cnts[N_PED];
  __shared__ int nxtA[N_PED], nxtB[N_PED];
  __shared__ int valL[N_PED], labL[N_PED], rankL[N_PED];
  __shared__ float wtL[96], wcL[10];
  const int n = threadIdx.x;

#pragma unroll
  for (int k = 0; k < 16; ++k) poolFix[k * N_PED + n] = 0;
  cnts[n] = 0;
  if (n < 96) wtL[n] = wt[n];
  if (n < 10) wcL[n] = wc[n];

  // rowcm = max over 12 tile-maxima (coalesced)
  int cm = -1;
#pragma unroll
  for (int j = 0; j < NW; ++j) {
    int t = rowmaxT[j * N_PED + n];
    cm = t > cm ? t : cm;
  }
  int v0 = (cm >= 0) ? cm : n;
  valL[n] = v0;

  // succ: first set bit in column v0 strictly after row n (self if none)
  int succ = n;
  {
    int j = n >> 6, rl = n & 63;
    unsigned long long w0 = (adjT[v0 * NW + j] >> rl) >> 1;
    if (w0) {
      succ = n + __ffsll(w0);
    } else {
      for (++j; j < NW; ++j) {
        unsigned long long ww = adjT[v0 * NW + j];
        if (ww) { succ = j * 64 + __ffsll(ww) - 1; break; }
      }
    }
  }
  nxtA[n] = succ;
  __syncthreads();

  int* src = nxtA;
  int* dst = nxtB;
#pragma unroll
  for (int it = 0; it < 10; ++it) {  // 2^10 >= 767
    dst[n] = src[src[n]];
    __syncthreads();
    int* t = src; src = dst; dst = t;
  }
  labL[n] = valL[src[n]];
  __syncthreads();

  // rank distinct labels ascending
  nxtA[n] = 0;
  __syncthreads();
  nxtA[labL[n]] = 1;
  __syncthreads();
  if (n < 64) {
    int f[NW], s = 0;
#pragma unroll
    for (int q = 0; q < NW; ++q) { f[q] = nxtA[n * NW + q]; s += f[q]; }
    int inc = s;
    for (int d = 1; d < 64; d <<= 1) {
      int t = __shfl_up(inc, d);
      if (n >= d) inc += t;
    }
    int run = inc - s;
#pragma unroll
    for (int q = 0; q < NW; ++q) { run += f[q]; rankL[n * NW + q] = run - 1; }
  }
  __syncthreads();
  const int g = rankL[labL[n]];

  // pooling: fixed-point atomics into own group slot
  float vv[16];
#pragma unroll
  for (int ct = 0; ct < 16; ++ct) vv[ct] = vrel[ct * N_PED + n];
#pragma unroll
  for (int ct = 0; ct < 16; ++ct) {
    long long fx = (long long)((double)vv[ct] * 4294967296.0);
    atomicAdd((unsigned long long*)&poolFix[ct * N_PED + g],
              (unsigned long long)fx);
  }
  atomicAdd(&cnts[n == n ? g : 0], 1);
  __syncthreads();

  // normalize in place -> double
  double* poolD = (double*)poolFix;
  {
    int cnt = cnts[n];
    double cinv = 1.0 / (double)(cnt > 1 ? cnt : 1);
#pragma unroll
    for (int ct = 0; ct < 16; ++ct) {
      long long fx = poolFix[ct * N_PED + n];
      poolD[ct * N_PED + n] = (double)fx * (1.0 / 4294967296.0) * cinv;
    }
  }
  __syncthreads();

  // epilogue: out[o,p,n] = (2*baseline(v_rel) + baseline(pool)[..,g]) / 3
  float pf[16];
#pragma unroll
  for (int ct = 0; ct < 16; ++ct) pf[ct] = (float)poolD[ct * N_PED + g];
  float tm1[2][12], tm2[2][12];
#pragma unroll
  for (int cc = 0; cc < 2; ++cc)
#pragma unroll
    for (int p = 0; p < 12; ++p) {
      float u1 = 0.f, u2 = 0.f;
#pragma unroll
      for (int t = 0; t < 8; ++t) {
        float wtv = wtL[t * 12 + p];
        u1 += wtv * vv[cc * 8 + t];
        u2 += wtv * pf[cc * 8 + t];
      }
      tm1[cc][p] = u1;
      tm2[cc][p] = u2;
    }
#pragma unroll
  for (int o = 0; o < 5; ++o)
#pragma unroll
    for (int p = 0; p < 12; ++p) {
      float v1 = wcL[0 * 5 + o] * tm1[0][p] + wcL[1 * 5 + o] * tm1[1][p];
      float v2 = wcL[0 * 5 + o] * tm2[0][p] + wcL[1 * 5 + o] * tm2[1][p];
      out[(o * 12 + p) * N_PED + n] = (v1 + v2 + v1) / 3.0f;
    }
}

extern "C" void kernel_launch(void* const* d_in, const int* in_sizes, int n_in,
                              void* d_out, int out_size, void* d_ws, size_t ws_size,
                              hipStream_t stream) {
  const float* va   = (const float*)d_in[0];
  const float* vr   = (const float*)d_in[1];
  const float* velw = (const float*)d_in[2];
  const float* velb = (const float*)d_in[3];
  const float* g1w  = (const float*)d_in[4];
  const float* g1b  = (const float*)d_in[5];
  const float* gam  = (const float*)d_in[6];
  const float* bet  = (const float*)d_in[7];
  const float* g2w  = (const float*)d_in[8];
  const float* g2b  = (const float*)d_in[9];
  const float* wt   = (const float*)d_in[10];
  const float* wc   = (const float*)d_in[11];
  float* out = (float*)d_out;

  char* ws = (char*)d_ws;
  unsigned short* adjT16 = (unsigned short*)(ws + 0);
  unsigned long long* adjT = (unsigned long long*)(ws + 0);
  int* rowmaxT = (int*)(ws + 73728);

  kb<<<576, 256, 0, stream>>>(va, vr, velw, velb, g1w, g1b, gam, bet, g2w, g2b,
                              adjT16, rowmaxT);
  kc<<<1, 768, 0, stream>>>(adjT, rowmaxT, vr, wt, wc, out);
}

// Round 9
// 30.425 us; speedup vs baseline: 1.4149x; 1.4149x over previous
//
#include <hip/hip_runtime.h>
#include <math.h>

#define N_PED 768
#define NW 12  // 768/64 u64 words per adjacency column

// ---------------- ws layout (bytes) ----------------
// adjT16  : [768*48] u16  @ 0       (73728)  column-major bits, 16-bit row-chunks
//           u64 view: word (c, I) at adjT[c*12+I]
// rowmaxT : [12][768] int @ 73728   (36864)  per-tile row max col (or -1)
// idx     : [768] int     @ 110592  (3072)
// pool    : [16][768] f32 @ 113664  (49152)  -> ends 162816

// KB: fused per-node features + pairwise dist + bit-transpose.
// Block = (tile I,J; row-chunk of 16 rows). Upper tiles (I<J) structurally
// zero: fill and exit. Compute blocks: recompute A (f64, exact reference
// ordering) for the 64 col nodes + 16 row nodes in LDS, then 4 waves x 4 rows
// of 64-lane pair evaluation -> ballot words -> u16 transpose store.
__global__ __launch_bounds__(256) void kb(
    const float* __restrict__ va, const float* __restrict__ vr,
    const float* __restrict__ velw, const float* __restrict__ velb,
    const float* __restrict__ g1w, const float* __restrict__ g1b,
    const float* __restrict__ gam, const float* __restrict__ bet,
    const float* __restrict__ g2w, const float* __restrict__ g2b,
    unsigned short* __restrict__ adjT16, int* __restrict__ rowmaxT) {
  int bid = blockIdx.x;
  int tile = bid >> 2, chunk = bid & 3;
  int I = tile / NW, J = tile % NW;
  int tid = threadIdx.x;
  if (I < J) {  // structurally zero
    if (tid < 64) adjT16[(J * 64 + tid) * 48 + I * 4 + chunk] = 0;
    if (tid < 16) rowmaxT[J * N_PED + I * 64 + chunk * 16 + tid] = -1;
    return;
  }
  __shared__ double Acol[16][64];
  __shared__ double Arow[16][16];
  __shared__ unsigned long long roww[16];

  // ---- A compute: jobs 0..63 col nodes, 64..79 row nodes; 2 threads/job ----
  {
    int job = tid >> 1, half = tid & 1;
    bool isrow = (job >= 64);
    bool active = (job < 80) && !(isrow && I == J);
    if (active) {
      int node = isrow ? (I * 64 + chunk * 16 + (job - 64)) : (J * 64 + job);
      double F[32];
#pragma unroll
      for (int cc = 0; cc < 2; ++cc)
#pragma unroll
        for (int t = 0; t < 8; ++t)
          F[cc * 8 + t] = (double)va[(cc * 8 + t) * N_PED + node];
#pragma unroll
      for (int o = 0; o < 2; ++o)
#pragma unroll
        for (int t = 0; t < 8; ++t)
          F[(2 + o) * 8 + t] = (double)velb[o]
              + (double)velw[o * 2 + 0] * (double)vr[(0 + t) * N_PED + node]
              + (double)velw[o * 2 + 1] * (double)vr[(8 + t) * N_PED + node];
      for (int o = half * 8; o < half * 8 + 8; ++o) {
        double s = 0.0;
#pragma unroll
        for (int k = 0; k < 32; ++k) s += (double)g1w[o * 32 + k] * F[k];
        if (isrow) Arow[o][job - 64] = s;
        else Acol[o][job] = s;
      }
    }
  }
  __syncthreads();

  // ---- effective MLP params (uniform, exact reference ordering) ----
  double w2[16], b1[16];
  const double inv_std = 1.0 / sqrt(1.0 + 1e-5);
#pragma unroll
  for (int o = 0; o < 16; ++o) {
    w2[o] = (double)g2w[o] * inv_std * (double)gam[o];
    b1[o] = (double)g1b[o];
  }
  double c0 = (double)g2b[0];
#pragma unroll
  for (int o = 0; o < 16; ++o) c0 += (double)g2w[o] * (double)bet[o];

  int w = tid >> 6, lane = tid & 63;
  int c = J * 64 + lane;
  double Ac[16];
#pragma unroll
  for (int o = 0; o < 16; ++o) Ac[o] = Acol[o][lane];

  for (int q = 0; q < 4; ++q) {
    int rr = w * 4 + q;
    int r = I * 64 + chunk * 16 + rr;
    double x1 = 0.0, x2 = 0.0;
#pragma unroll
    for (int o = 0; o < 16; ++o) {
      double Av = (I == J) ? Acol[o][chunk * 16 + rr] : Arow[o][rr];
      double s = Av - Ac[o];
      x1 += w2[o] * fmax(s + b1[o], 0.0);
      x2 += w2[o] * fmax(b1[o] - s, 0.0);
    }
    double dist = 0.5 * (exp(x1 + c0) + exp(x2 + c0));
    bool bit = (c < r) && (dist <= 1.0);
    unsigned long long word = __ballot(bit ? 1 : 0);
    if (lane == 0) {
      roww[rr] = word;
      rowmaxT[J * N_PED + r] =
          word ? (J * 64 + 63 - __clzll((long long)word)) : -1;
    }
  }
  __syncthreads();

  if (tid < 64) {  // transpose 16 rows x 64 cols -> u16 per col
    unsigned m = 0;
#pragma unroll
    for (int rr = 0; rr < 16; ++rr)
      m |= (unsigned)((roww[rr] >> tid) & 1ull) << rr;
    adjT16[(J * 64 + tid) * 48 + I * 4 + chunk] = (unsigned short)m;
  }
}

// K3: pointer-doubling over the successor forest (proved R4):
//   v0[n]   = rowcm[n] >= 0 ? rowcm[n] : n
//   succ(n) = first set bit in column v0[n] strictly below row n (self if none)
//   label(n) = v0 at root; labels ranked ascending -> group ids.
__global__ __launch_bounds__(768) void k3s(
    const unsigned long long* __restrict__ adjT,
    const int* __restrict__ rowmaxT, int* __restrict__ out_idx) {
  __shared__ int nxtA[N_PED], nxtB[N_PED];
  __shared__ int valL[N_PED], labL[N_PED], rankL[N_PED];
  const int n = threadIdx.x;

  int cm = -1;
#pragma unroll
  for (int j = 0; j < NW; ++j) {
    int t = rowmaxT[j * N_PED + n];
    cm = t > cm ? t : cm;
  }
  int v0 = (cm >= 0) ? cm : n;
  valL[n] = v0;

  int succ = n;
  {
    int j = n >> 6, rl = n & 63;
    unsigned long long w0 = (adjT[v0 * NW + j] >> rl) >> 1;
    if (w0) {
      succ = n + __ffsll(w0);
    } else {
      for (++j; j < NW; ++j) {
        unsigned long long ww = adjT[v0 * NW + j];
        if (ww) { succ = j * 64 + __ffsll(ww) - 1; break; }
      }
    }
  }
  nxtA[n] = succ;
  __syncthreads();

  int* src = nxtA;
  int* dst = nxtB;
#pragma unroll
  for (int it = 0; it < 10; ++it) {  // 2^10 >= 767
    dst[n] = src[src[n]];
    __syncthreads();
    int* t = src; src = dst; dst = t;
  }
  labL[n] = valL[src[n]];
  __syncthreads();

  nxtA[n] = 0;  // reuse as flags
  __syncthreads();
  nxtA[labL[n]] = 1;
  __syncthreads();
  if (n < 64) {  // wave 0: 12-segment scan ranks distinct labels ascending
    int f[NW], s = 0;
#pragma unroll
    for (int q = 0; q < NW; ++q) { f[q] = nxtA[n * NW + q]; s += f[q]; }
    int inc = s;
    for (int d = 1; d < 64; d <<= 1) {
      int t = __shfl_up(inc, d);
      if (n >= d) inc += t;
    }
    int run = inc - s;
#pragma unroll
    for (int q = 0; q < NW; ++q) { run += f[q]; rankL[n * NW + q] = run - 1; }
  }
  __syncthreads();
  out_idx[n] = rankL[labL[n]];
}

// K4: group-mean pooling, one wave per (ct, g); shfl_xor tree reduce.
__global__ __launch_bounds__(256) void k4_pool(
    const float* __restrict__ vrel, const int* __restrict__ idx,
    float* __restrict__ pool) {
  int wv = blockIdx.x * 4 + (threadIdx.x >> 6);  // 0..12287
  int lane = threadIdx.x & 63;
  int ct = wv / N_PED;
  int g = wv % N_PED;
  float s = 0.f;
  int cnt = 0;
#pragma unroll
  for (int k = 0; k < NW; ++k) {
    int n = k * 64 + lane;
    int id = idx[n];
    float v = vrel[ct * N_PED + n];
    bool m = (id == g);
    s += m ? v : 0.f;
    cnt += m ? 1 : 0;
  }
#pragma unroll
  for (int d = 1; d < 64; d <<= 1) {
    s += __shfl_xor(s, d);
    cnt += __shfl_xor(cnt, d);
  }
  if (lane == 0) pool[ct * N_PED + g] = s / fmaxf((float)cnt, 1.0f);
}

// K5: out[o,p,n] = (2*baseline(v_rel) + baseline(pool)[..,idx[n]]) / 3
__global__ __launch_bounds__(256) void k5_final(
    const float* __restrict__ vrel, const float* __restrict__ pool,
    const int* __restrict__ idx, const float* __restrict__ wt,
    const float* __restrict__ wc, float* __restrict__ out) {
  int i = blockIdx.x * 256 + threadIdx.x;
  if (i >= 5 * 12 * N_PED) return;
  int n = i % N_PED;
  int t_ = i / N_PED;
  int p = t_ % 12;
  int o = t_ / 12;
  int g = idx[n];
  float v1 = 0.f, v2 = 0.f;
#pragma unroll
  for (int c = 0; c < 2; ++c) {
    float u1 = 0.f, u2 = 0.f;
#pragma unroll
    for (int t = 0; t < 8; ++t) {
      float wtv = wt[t * 12 + p];
      u1 += wtv * vrel[(c * 8 + t) * N_PED + n];
      u2 += wtv * pool[(c * 8 + t) * N_PED + g];
    }
    float wcv = wc[c * 5 + o];
    v1 += wcv * u1;
    v2 += wcv * u2;
  }
  out[i] = (v1 + v2 + v1) / 3.0f;
}

extern "C" void kernel_launch(void* const* d_in, const int* in_sizes, int n_in,
                              void* d_out, int out_size, void* d_ws, size_t ws_size,
                              hipStream_t stream) {
  const float* va   = (const float*)d_in[0];
  const float* vr   = (const float*)d_in[1];
  const float* velw = (const float*)d_in[2];
  const float* velb = (const float*)d_in[3];
  const float* g1w  = (const float*)d_in[4];
  const float* g1b  = (const float*)d_in[5];
  const float* gam  = (const float*)d_in[6];
  const float* bet  = (const float*)d_in[7];
  const float* g2w  = (const float*)d_in[8];
  const float* g2b  = (const float*)d_in[9];
  const float* wt   = (const float*)d_in[10];
  const float* wc   = (const float*)d_in[11];
  float* out = (float*)d_out;

  char* ws = (char*)d_ws;
  unsigned short* adjT16 = (unsigned short*)(ws + 0);
  unsigned long long* adjT = (unsigned long long*)(ws + 0);
  int* rowmaxT = (int*)(ws + 73728);
  int* idx = (int*)(ws + 110592);
  float* pool = (float*)(ws + 113664);

  kb<<<576, 256, 0, stream>>>(va, vr, velw, velb, g1w, g1b, gam, bet, g2w, g2b,
                              adjT16, rowmaxT);
  k3s<<<1, 768, 0, stream>>>(adjT, rowmaxT, idx);
  k4_pool<<<3072, 256, 0, stream>>>(vr, idx, pool);
  k5_final<<<180, 256, 0, stream>>>(vr, pool, idx, wt, wc, out);
}